// Round 8
// baseline (335.446 us; speedup 1.0000x reference)
//
#include <hip/hip_runtime.h>
#include <hip/hip_cooperative_groups.h>

namespace cg = cooperative_groups;

#define EPS 1e-5f

typedef __bf16 bf16x8 __attribute__((ext_vector_type(8)));
typedef float f32x4 __attribute__((ext_vector_type(4)));

union BF8 { bf16x8 v; unsigned short u[8]; uint4 q; };

__device__ inline unsigned short f32_to_bf16(float f) {
    unsigned u = __builtin_bit_cast(unsigned, f);
    return (unsigned short)((u + 0x7FFFu + ((u >> 16) & 1u)) >> 16);
}
__device__ inline float relu6f(float x) { return fminf(fmaxf(x, 0.f), 6.f); }

// ===================== phase 1: x1 = u8quant(relu6(bn1(feats @ W1))) =====================
struct P1 { bf16x8 bf[12]; float s[12], b[12]; };

__device__ __forceinline__ void p1_init(P1& st,
    const float* __restrict__ W1, const float* __restrict__ g1,
    const float* __restrict__ b1, const float* __restrict__ m1,
    const float* __restrict__ v1, int m, int q)
{
    const float Q = 255.f / 6.f;
#pragma unroll
    for (int t = 0; t < 12; ++t) {
        int c = 16 * t + m;
        BF8 tmp;
#pragma unroll
        for (int j = 0; j < 8; ++j)
            tmp.u[j] = f32_to_bf16(W1[(q * 8 + j) * 192 + c]);
        st.bf[t] = tmp.v;
        float s = g1[c] * rsqrtf(v1[c] + EPS);
        st.s[t] = s * Q;
        st.b[t] = (b1[c] - m1[c] * s) * Q;
    }
}

// outB: 48*224 u8 = 10752 B. Two __syncthreads inside (outB reuse across tiles).
__device__ __forceinline__ void p1_tile(const P1& st, int tile, int N,
    const float* __restrict__ feats, unsigned char* __restrict__ x1,
    unsigned char* outB, int tid)
{
    const int lane = tid & 63, wave = tid >> 6;
    const int m = lane & 15, q = lane >> 4;
    const int rowbase = tile * 48;
    const int row = rowbase + wave * 16 + m;

    float4 f0 = {0.f,0.f,0.f,0.f}, f1v = {0.f,0.f,0.f,0.f};
    if (row < N) {
        f0  = *(const float4*)(feats + (size_t)row * 32 + q * 8);
        f1v = *(const float4*)(feats + (size_t)row * 32 + q * 8 + 4);
    }
    BF8 af;
    af.u[0] = f32_to_bf16(f0.x);  af.u[1] = f32_to_bf16(f0.y);
    af.u[2] = f32_to_bf16(f0.z);  af.u[3] = f32_to_bf16(f0.w);
    af.u[4] = f32_to_bf16(f1v.x); af.u[5] = f32_to_bf16(f1v.y);
    af.u[6] = f32_to_bf16(f1v.z); af.u[7] = f32_to_bf16(f1v.w);

#pragma unroll
    for (int t = 0; t < 12; ++t) {
        f32x4 z = {0.f, 0.f, 0.f, 0.f};
        f32x4 acc = __builtin_amdgcn_mfma_f32_16x16x32_bf16(af.v, st.bf[t], z, 0, 0, 0);
        int c = 16 * t + m;
#pragma unroll
        for (int i = 0; i < 4; ++i) {
            float y = fmaf(acc[i], st.s[t], st.b[t]);
            y = fminf(fmaxf(y, 0.f), 255.f);
            outB[(wave * 16 + q * 4 + i) * 224 + c] = (unsigned char)(y + 0.5f);
        }
    }
    __syncthreads();
    // readout: wave-private rows, contiguous uint4 stores
#pragma unroll
    for (int j = 0; j < 3; ++j) {
        int i = j * 64 + lane;               // 0..191 within wave region
        int r = i / 12, c = i % 12;
        int grow = rowbase + wave * 16 + r;
        if (grow < N)
            *(uint4*)(x1 + (size_t)grow * 192 + c * 16) =
                *(const uint4*)(&outB[(wave * 16 + r) * 224 + c * 16]);
    }
    __syncthreads();
}

// ====== phase 2: depthwise gather (u8) + bn2 + relu6 + project MFMA + bn3 + residual ======
struct P2 {
    float w2v[9][4];
    float s2[4], bb2[4];
    bf16x8 bfrag[12];
    float s3c[2], bb3c[2];
};

__device__ __forceinline__ void p2_init(P2& st,
    const float* __restrict__ W2, const float* __restrict__ W3,
    const float* __restrict__ g2, const float* __restrict__ b2,
    const float* __restrict__ m2, const float* __restrict__ v2,
    const float* __restrict__ g3, const float* __restrict__ b3,
    const float* __restrict__ m3, const float* __restrict__ v3,
    int tid)
{
    const int cgi = tid % 48;
    const int c0 = cgi * 4;
    const int lane = tid & 63;
    const int m = lane & 15, q = lane >> 4;
    const float DQ = 6.f / 255.f;
#pragma unroll
    for (int k = 0; k < 9; ++k) {
        float4 w = *(const float4*)(W2 + k * 192 + c0);
        st.w2v[k][0] = w.x * DQ; st.w2v[k][1] = w.y * DQ;
        st.w2v[k][2] = w.z * DQ; st.w2v[k][3] = w.w * DQ;
    }
#pragma unroll
    for (int j = 0; j < 4; ++j) {
        int c = c0 + j;
        float u = g2[c] * rsqrtf(v2[c] + EPS);
        st.s2[j] = u; st.bb2[j] = b2[c] - m2[c] * u;
    }
#pragma unroll
    for (int s = 0; s < 6; ++s)
#pragma unroll
        for (int t = 0; t < 2; ++t) {
            BF8 tmp;
#pragma unroll
            for (int j = 0; j < 8; ++j)
                tmp.u[j] = f32_to_bf16(W3[(32 * s + q * 8 + j) * 32 + 16 * t + m]);
            st.bfrag[s * 2 + t] = tmp.v;
        }
#pragma unroll
    for (int t = 0; t < 2; ++t) {
        int c = 16 * t + m;
        float w = g3[c] * rsqrtf(v3[c] + EPS);
        st.s3c[t] = w; st.bb3c[t] = b3[c] - m3[c] * w;
    }
}

// x2L: 48*200 u16 = 19200 B; offL: 48*12 int = 2304 B. Two __syncthreads inside.
__device__ __forceinline__ void p2_tile(const P2& st, int tile, int N,
    const unsigned char* __restrict__ x1, const int* __restrict__ nbr,
    const float* __restrict__ feats, float* __restrict__ out,
    unsigned short* x2L, int* offL, int tid)
{
    const int rowbase = tile * 48;
    const int cgi = tid % 48;
    const int slot = tid / 48;
    const int c0 = cgi * 4;
    const char* x1b = (const char*)x1 + c0;
    const int lane = tid & 63, wave = tid >> 6;
    const int m = lane & 15, q = lane >> 4;

    for (int i = tid; i < 432; i += 192) {
        int r = i / 9, k = i - r * 9;
        int n = rowbase + r;
        int idx = (n < N) ? nbr[(size_t)n * 9 + k] : -1;
        offL[r * 12 + k] = (idx < 0) ? -1 : idx * 192;
    }
    __syncthreads();

#pragma unroll
    for (int it = 0; it < 6; ++it) {
        int r0 = it * 8 + slot, r1 = r0 + 4;
        const int* nA = &offL[r0 * 12];
        const int* nB = &offL[r1 * 12];
        int4 a03 = *(const int4*)nA; int4 a47 = *(const int4*)(nA + 4); int a8 = nA[8];
        int4 b03 = *(const int4*)nB; int4 b47 = *(const int4*)(nB + 4); int b8 = nB[8];
        int offA[9] = {a03.x, a03.y, a03.z, a03.w, a47.x, a47.y, a47.z, a47.w, a8};
        int offB[9] = {b03.x, b03.y, b03.z, b03.w, b47.x, b47.y, b47.z, b47.w, b8};
        unsigned gA[9], gB[9];
#pragma unroll
        for (int k = 0; k < 9; ++k) {
            gA[k] = *(const unsigned*)(x1b + (offA[k] < 0 ? 0 : offA[k]));
            gB[k] = *(const unsigned*)(x1b + (offB[k] < 0 ? 0 : offB[k]));
        }
        float a0 = 0.f, a1 = 0.f, a2 = 0.f, a3 = 0.f;
        float c0f = 0.f, c1 = 0.f, c2 = 0.f, c3 = 0.f;
#pragma unroll
        for (int k = 0; k < 9; ++k) {
            unsigned ga = offA[k] >= 0 ? gA[k] : 0u;
            unsigned gb = offB[k] >= 0 ? gB[k] : 0u;
            a0 = fmaf((float)(ga & 0xFF),         st.w2v[k][0], a0);
            a1 = fmaf((float)((ga >> 8) & 0xFF),  st.w2v[k][1], a1);
            a2 = fmaf((float)((ga >> 16) & 0xFF), st.w2v[k][2], a2);
            a3 = fmaf((float)(ga >> 24),          st.w2v[k][3], a3);
            c0f = fmaf((float)(gb & 0xFF),         st.w2v[k][0], c0f);
            c1  = fmaf((float)((gb >> 8) & 0xFF),  st.w2v[k][1], c1);
            c2  = fmaf((float)((gb >> 16) & 0xFF), st.w2v[k][2], c2);
            c3  = fmaf((float)(gb >> 24),          st.w2v[k][3], c3);
        }
        a0 = relu6f(fmaf(a0, st.s2[0], st.bb2[0]));
        a1 = relu6f(fmaf(a1, st.s2[1], st.bb2[1]));
        a2 = relu6f(fmaf(a2, st.s2[2], st.bb2[2]));
        a3 = relu6f(fmaf(a3, st.s2[3], st.bb2[3]));
        c0f = relu6f(fmaf(c0f, st.s2[0], st.bb2[0]));
        c1  = relu6f(fmaf(c1,  st.s2[1], st.bb2[1]));
        c2  = relu6f(fmaf(c2,  st.s2[2], st.bb2[2]));
        c3  = relu6f(fmaf(c3,  st.s2[3], st.bb2[3]));
        uint2 pA, pB;
        pA.x = (unsigned)f32_to_bf16(a0) | ((unsigned)f32_to_bf16(a1) << 16);
        pA.y = (unsigned)f32_to_bf16(a2) | ((unsigned)f32_to_bf16(a3) << 16);
        pB.x = (unsigned)f32_to_bf16(c0f) | ((unsigned)f32_to_bf16(c1) << 16);
        pB.y = (unsigned)f32_to_bf16(c2)  | ((unsigned)f32_to_bf16(c3) << 16);
        *(uint2*)(&x2L[r0 * 200 + c0]) = pA;
        *(uint2*)(&x2L[r1 * 200 + c0]) = pB;
    }
    __syncthreads();

    f32x4 acc0 = {0.f, 0.f, 0.f, 0.f}, acc1 = {0.f, 0.f, 0.f, 0.f};
    const int rw = wave * 16;
#pragma unroll
    for (int s = 0; s < 6; ++s) {
        bf16x8 a = *reinterpret_cast<const bf16x8*>(&x2L[(rw + m) * 200 + 32 * s + q * 8]);
        acc0 = __builtin_amdgcn_mfma_f32_16x16x32_bf16(a, st.bfrag[s * 2 + 0], acc0, 0, 0, 0);
        acc1 = __builtin_amdgcn_mfma_f32_16x16x32_bf16(a, st.bfrag[s * 2 + 1], acc1, 0, 0, 0);
    }

#pragma unroll
    for (int t = 0; t < 2; ++t) {
        f32x4 acc = (t == 0) ? acc0 : acc1;
        int c = 16 * t + m;
#pragma unroll
        for (int i = 0; i < 4; ++i) {
            int r = rowbase + rw + q * 4 + i;
            if (r < N) {
                int o = r * 32 + c;
                out[o] = fmaf(acc[i], st.s3c[t], st.bb3c[t]) + feats[o];
            }
        }
    }
}

// ===================== cooperative fused kernel =====================
// LDS union: phase1 outB (10752 B) aliases phase2 x2L (19200 B) + offL (2304 B) = 21504 B.
__global__ __launch_bounds__(192, 3) void fused_coop(
    const float* __restrict__ feats, const int* __restrict__ nbr,
    const float* __restrict__ W1, const float* __restrict__ W2,
    const float* __restrict__ W3,
    const float* __restrict__ g1, const float* __restrict__ b1,
    const float* __restrict__ m1, const float* __restrict__ v1,
    const float* __restrict__ g2, const float* __restrict__ b2,
    const float* __restrict__ m2, const float* __restrict__ v2,
    const float* __restrict__ g3, const float* __restrict__ b3,
    const float* __restrict__ m3, const float* __restrict__ v3,
    unsigned char* __restrict__ x1, float* __restrict__ out,
    int N, int nTiles)
{
    __shared__ __align__(16) unsigned char smem[21504];
    const int tid = threadIdx.x;
    const int lane = tid & 63;
    const int m = lane & 15, q = lane >> 4;

    {
        P1 p1;
        p1_init(p1, W1, g1, b1, m1, v1, m, q);
        for (int tile = blockIdx.x; tile < nTiles; tile += gridDim.x)
            p1_tile(p1, tile, N, feats, x1, smem, tid);
    }

    cg::this_grid().sync();

    {
        P2 p2;
        p2_init(p2, W2, W3, g2, b2, m2, v2, g3, b3, m3, v3, tid);
        unsigned short* x2L = (unsigned short*)smem;
        int* offL = (int*)(smem + 19200);
        for (int tile = blockIdx.x; tile < nTiles; tile += gridDim.x)
            p2_tile(p2, tile, N, x1, nbr, feats, out, x2L, offL, tid);
    }
}

// ===================== fallback: 2 plain kernels (same device code) =====================
__global__ __launch_bounds__(192) void k1f(
    const float* __restrict__ feats,
    const float* __restrict__ W1,
    const float* __restrict__ g1, const float* __restrict__ b1,
    const float* __restrict__ m1, const float* __restrict__ v1,
    unsigned char* __restrict__ x1, int N)
{
    __shared__ __align__(16) unsigned char outB[48 * 224];
    const int tid = threadIdx.x;
    const int lane = tid & 63;
    P1 p1;
    p1_init(p1, W1, g1, b1, m1, v1, lane & 15, lane >> 4);
    p1_tile(p1, blockIdx.x, N, feats, x1, outB, tid);
}

__global__ __launch_bounds__(192) void k2f(
    const unsigned char* __restrict__ x1, const int* __restrict__ nbr,
    const float* __restrict__ W2, const float* __restrict__ W3,
    const float* __restrict__ g2, const float* __restrict__ b2,
    const float* __restrict__ m2, const float* __restrict__ v2,
    const float* __restrict__ g3, const float* __restrict__ b3,
    const float* __restrict__ m3, const float* __restrict__ v3,
    const float* __restrict__ feats, float* __restrict__ out, int N)
{
    __shared__ __align__(16) unsigned short x2L[48 * 200];
    __shared__ __align__(16) int offL[48 * 12];
    const int tid = threadIdx.x;
    P2 p2;
    p2_init(p2, W2, W3, g2, b2, m2, v2, g3, b3, m3, v3, tid);
    p2_tile(p2, blockIdx.x, N, x1, nbr, feats, out, x2L, offL, tid);
}

extern "C" void kernel_launch(void* const* d_in, const int* in_sizes, int n_in,
                              void* d_out, int out_size, void* d_ws, size_t ws_size,
                              hipStream_t stream) {
    const float* feats = (const float*)d_in[0];
    const int*   nbr   = (const int*)d_in[1];
    const float* W1    = (const float*)d_in[2];
    const float* W2    = (const float*)d_in[3];
    const float* W3    = (const float*)d_in[4];
    const float* g1 = (const float*)d_in[5];
    const float* b1 = (const float*)d_in[6];
    const float* m1 = (const float*)d_in[7];
    const float* v1 = (const float*)d_in[8];
    const float* g2 = (const float*)d_in[9];
    const float* b2 = (const float*)d_in[10];
    const float* m2 = (const float*)d_in[11];
    const float* v2 = (const float*)d_in[12];
    const float* g3 = (const float*)d_in[13];
    const float* b3 = (const float*)d_in[14];
    const float* m3 = (const float*)d_in[15];
    const float* v3 = (const float*)d_in[16];
    float* out = (float*)d_out;

    int N = in_sizes[0] / 32;
    int nTiles = (N + 47) / 48;
    unsigned char* x1 = (unsigned char*)d_ws;   // N*192 u8 = 38.4 MB

    // size coop grid from the runtime's own occupancy math (R6 failed with a guessed grid)
    int occ = 0;
    hipError_t eo = hipOccupancyMaxActiveBlocksPerMultiprocessor(
        &occ, (const void*)fused_coop, 192, 0);
    int dev = 0, nCU = 0;
    hipGetDevice(&dev);
    hipDeviceGetAttribute(&nCU, hipDeviceAttributeMultiprocessorCount, dev);
    if (nCU <= 0) nCU = 256;

    bool coop_done = false;
    if (eo == hipSuccess && occ > 0) {
        int grid = occ * nCU;
        if (grid > nTiles) grid = nTiles;
        if (grid < 1) grid = 1;
        void* args[] = {
            (void*)&feats, (void*)&nbr, (void*)&W1, (void*)&W2, (void*)&W3,
            (void*)&g1, (void*)&b1, (void*)&m1, (void*)&v1,
            (void*)&g2, (void*)&b2, (void*)&m2, (void*)&v2,
            (void*)&g3, (void*)&b3, (void*)&m3, (void*)&v3,
            (void*)&x1, (void*)&out, (void*)&N, (void*)&nTiles
        };
        hipError_t el = hipLaunchCooperativeKernel(
            (const void*)fused_coop, dim3(grid), dim3(192), args, 0, stream);
        coop_done = (el == hipSuccess);
    }

    if (!coop_done) {
        // proven 2-kernel path (~R6-level perf)
        k1f<<<dim3(nTiles), dim3(192), 0, stream>>>(
            feats, W1, g1, b1, m1, v1, x1, N);
        k2f<<<dim3(nTiles), dim3(192), 0, stream>>>(
            x1, nbr, W2, W3, g2, b2, m2, v2, g3, b3, m3, v3, feats, out, N);
    }
}

// Round 10
// 206.361 us; speedup vs baseline: 1.6255x; 1.6255x over previous
//
#include <hip/hip_runtime.h>

#define EPS 1e-5f

typedef __bf16 bf16x8 __attribute__((ext_vector_type(8)));
typedef float f32x4 __attribute__((ext_vector_type(4)));

union BF8 { bf16x8 v; unsigned short u[8]; uint4 q; };

__device__ inline unsigned short f32_to_bf16(float f) {
    unsigned u = __builtin_bit_cast(unsigned, f);
    return (unsigned short)((u + 0x7FFFu + ((u >> 16) & 1u)) >> 16);
}
__device__ inline float relu6f(float x) { return fminf(fmaxf(x, 0.f), 6.f); }

// ---- K0: one-time prep. w1t = W1^T bf16 [192][32]; w3t = W3^T bf16 [32][192];
//      bnc = {s1*42.5[192], b1'*42.5[192], s2[192], b2'[192], s3[32], b3'[32]}
__global__ __launch_bounds__(256) void k0_prep(
    const float* __restrict__ W1, const float* __restrict__ W3,
    const float* __restrict__ g1, const float* __restrict__ b1,
    const float* __restrict__ m1, const float* __restrict__ v1,
    const float* __restrict__ g2, const float* __restrict__ b2,
    const float* __restrict__ m2, const float* __restrict__ v2,
    const float* __restrict__ g3, const float* __restrict__ b3,
    const float* __restrict__ m3, const float* __restrict__ v3,
    unsigned short* __restrict__ w1t, unsigned short* __restrict__ w3t,
    float* __restrict__ bnc)
{
    const int gtid = blockIdx.x * 256 + threadIdx.x;
    const int gstr = gridDim.x * 256;
    for (int i = gtid; i < 6144; i += gstr) {          // w1t[n*32+k] = W1[k*192+n]
        int n = i >> 5, k = i & 31;
        w1t[i] = f32_to_bf16(W1[k * 192 + n]);
    }
    for (int i = gtid; i < 6144; i += gstr) {          // w3t[n*192+k] = W3[k*32+n]
        int n = i / 192, k = i - n * 192;
        w3t[i] = f32_to_bf16(W3[k * 32 + n]);
    }
    if (blockIdx.x == 0) {
        int t = threadIdx.x;
        const float Q = 255.f / 6.f;
        if (t < 192) {
            float s = g1[t] * rsqrtf(v1[t] + EPS);
            bnc[t] = s * Q; bnc[192 + t] = (b1[t] - m1[t] * s) * Q;
            float u = g2[t] * rsqrtf(v2[t] + EPS);
            bnc[384 + t] = u; bnc[576 + t] = b2[t] - m2[t] * u;
            if (t < 32) {
                float w = g3[t] * rsqrtf(v3[t] + EPS);
                bnc[768 + t] = w; bnc[800 + t] = b3[t] - m3[t] * w;
            }
        }
    }
}

// ---------------- K1: x1 = uint8-quant(relu6(bn1(feats @ W1))), MFMA ----------------
// 64 rows/block, 256 threads, ZERO LDS / barriers. Epilogue: in-register 4x4 byte
// transpose (2x shfl_xor -> DPP quad-perm, 2x v_perm_b32) converts the C-layout
// (1 col x 4 rows per lane) into (1 row x 4 cols) -> direct dword stores to global.
__global__ __launch_bounds__(256) void k1_expand(
    const float* __restrict__ feats, const unsigned short* __restrict__ w1t,
    const float* __restrict__ bnc, unsigned char* __restrict__ x1, int N)
{
    const int tid = threadIdx.x;
    const int rowbase = blockIdx.x * 64;
    const int lane = tid & 63, wave = tid >> 6;
    const int m = lane & 15, q = lane >> 4;

    // B-frags from L2-hot w1t (b128 x12)
    bf16x8 bf[12];
#pragma unroll
    for (int t = 0; t < 12; ++t)
        bf[t] = *(const bf16x8*)(w1t + (16 * t + m) * 32 + q * 8);

    // A-frag straight from global (wave covers a contiguous 2KB)
    const int arow = rowbase + wave * 16 + m;
    float4 f0 = {0.f,0.f,0.f,0.f}, f1v = {0.f,0.f,0.f,0.f};
    if (arow < N) {
        f0  = *(const float4*)(feats + (size_t)arow * 32 + q * 8);
        f1v = *(const float4*)(feats + (size_t)arow * 32 + q * 8 + 4);
    }
    BF8 af;
    af.u[0] = f32_to_bf16(f0.x);  af.u[1] = f32_to_bf16(f0.y);
    af.u[2] = f32_to_bf16(f0.z);  af.u[3] = f32_to_bf16(f0.w);
    af.u[4] = f32_to_bf16(f1v.x); af.u[5] = f32_to_bf16(f1v.y);
    af.u[6] = f32_to_bf16(f1v.z); af.u[7] = f32_to_bf16(f1v.w);

    f32x4 acc[12];
#pragma unroll
    for (int t = 0; t < 12; ++t) {
        f32x4 z = {0.f, 0.f, 0.f, 0.f};
        acc[t] = __builtin_amdgcn_mfma_f32_16x16x32_bf16(af.v, bf[t], z, 0, 0, 0);
    }

    // transpose selectors (verified byte-level: lane b of each 4-lane group ends
    // holding row 4q+b, cols 16t+4a..+3, a=(lane>>2)&3)
    const unsigned sel1 = (lane & 1) ? 0x03070105u : 0x06020400u;
    const unsigned sel2 = (lane & 2) ? 0x03020706u : 0x05040100u;
    const int rowg = rowbase + wave * 16 + 4 * q + (lane & 3);
    const int colb = 4 * ((lane >> 2) & 3);

#pragma unroll
    for (int t = 0; t < 12; ++t) {
        int c = 16 * t + m;
        float s = bnc[c], bb = bnc[192 + c];     // quant scale folded by k0
        unsigned b[4];
#pragma unroll
        for (int i = 0; i < 4; ++i) {
            float y = fmaf(acc[t][i], s, bb);
            y = fminf(fmaxf(y, 0.f), 255.f);
            b[i] = (unsigned)(y + 0.5f);
        }
        unsigned D = b[0] | (b[1] << 8) | (b[2] << 16) | (b[3] << 24);
        unsigned e  = __builtin_amdgcn_perm((unsigned)__shfl_xor((int)D, 1), D, sel1);
        unsigned tr = __builtin_amdgcn_perm((unsigned)__shfl_xor((int)e, 2), e, sel2);
        if (rowg < N)
            *(unsigned*)(x1 + (size_t)rowg * 192 + 16 * t + colb) = tr;
    }
}

// ------- K2: fused depthwise gather (u8) + bn2 + relu6 + project GEMM + bn3 + residual -------
// (verbatim R6 — proven 78 us; untouched for attribution)
__global__ __launch_bounds__(192) void k2_fused(
    const unsigned char* __restrict__ x1, const int* __restrict__ nbr,
    const float* __restrict__ W2, const unsigned short* __restrict__ w3t,
    const float* __restrict__ bnc, const float* __restrict__ feats,
    float* __restrict__ out, int N)
{
    __shared__ __align__(16) unsigned short x2L[48 * 200];
    __shared__ __align__(16) int offL[48 * 12];
    const int tid = threadIdx.x;
    const int rowbase = blockIdx.x * 48;

    for (int i = tid; i < 432; i += 192) {
        int r = i / 9, k = i - r * 9;
        int n = rowbase + r;
        int idx = (n < N) ? nbr[(size_t)n * 9 + k] : -1;
        offL[r * 12 + k] = (idx < 0) ? -1 : idx * 192;
    }

    const int cg = tid % 48;
    const int slot = tid / 48;
    const int c0 = cg * 4;
    const char* x1b = (const char*)x1 + c0;

    const float DQ = 6.f / 255.f;
    float w2v[9][4];
#pragma unroll
    for (int k = 0; k < 9; ++k) {
        float4 w = *(const float4*)(W2 + k * 192 + c0);
        w2v[k][0] = w.x * DQ; w2v[k][1] = w.y * DQ; w2v[k][2] = w.z * DQ; w2v[k][3] = w.w * DQ;
    }
    float4 s2 = *(const float4*)(bnc + 384 + c0);
    float4 bb2 = *(const float4*)(bnc + 576 + c0);
    __syncthreads();

#pragma unroll
    for (int it = 0; it < 6; ++it) {
        int r0 = it * 8 + slot, r1 = r0 + 4;
        const int* nA = &offL[r0 * 12];
        const int* nB = &offL[r1 * 12];
        int4 a03 = *(const int4*)nA; int4 a47 = *(const int4*)(nA + 4); int a8 = nA[8];
        int4 b03 = *(const int4*)nB; int4 b47 = *(const int4*)(nB + 4); int b8 = nB[8];
        int offA[9] = {a03.x, a03.y, a03.z, a03.w, a47.x, a47.y, a47.z, a47.w, a8};
        int offB[9] = {b03.x, b03.y, b03.z, b03.w, b47.x, b47.y, b47.z, b47.w, b8};
        unsigned gA[9], gB[9];
#pragma unroll
        for (int k = 0; k < 9; ++k) {
            gA[k] = *(const unsigned*)(x1b + (offA[k] < 0 ? 0 : offA[k]));
            gB[k] = *(const unsigned*)(x1b + (offB[k] < 0 ? 0 : offB[k]));
        }
        float a0 = 0.f, a1 = 0.f, a2 = 0.f, a3 = 0.f;
        float c0f = 0.f, c1 = 0.f, c2 = 0.f, c3 = 0.f;
#pragma unroll
        for (int k = 0; k < 9; ++k) {
            unsigned ga = offA[k] >= 0 ? gA[k] : 0u;
            unsigned gb = offB[k] >= 0 ? gB[k] : 0u;
            a0 = fmaf((float)(ga & 0xFF),         w2v[k][0], a0);
            a1 = fmaf((float)((ga >> 8) & 0xFF),  w2v[k][1], a1);
            a2 = fmaf((float)((ga >> 16) & 0xFF), w2v[k][2], a2);
            a3 = fmaf((float)(ga >> 24),          w2v[k][3], a3);
            c0f = fmaf((float)(gb & 0xFF),         w2v[k][0], c0f);
            c1  = fmaf((float)((gb >> 8) & 0xFF),  w2v[k][1], c1);
            c2  = fmaf((float)((gb >> 16) & 0xFF), w2v[k][2], c2);
            c3  = fmaf((float)(gb >> 24),          w2v[k][3], c3);
        }
        a0 = relu6f(fmaf(a0, s2.x, bb2.x));
        a1 = relu6f(fmaf(a1, s2.y, bb2.y));
        a2 = relu6f(fmaf(a2, s2.z, bb2.z));
        a3 = relu6f(fmaf(a3, s2.w, bb2.w));
        c0f = relu6f(fmaf(c0f, s2.x, bb2.x));
        c1  = relu6f(fmaf(c1,  s2.y, bb2.y));
        c2  = relu6f(fmaf(c2,  s2.z, bb2.z));
        c3  = relu6f(fmaf(c3,  s2.w, bb2.w));
        uint2 pA, pB;
        pA.x = (unsigned)f32_to_bf16(a0) | ((unsigned)f32_to_bf16(a1) << 16);
        pA.y = (unsigned)f32_to_bf16(a2) | ((unsigned)f32_to_bf16(a3) << 16);
        pB.x = (unsigned)f32_to_bf16(c0f) | ((unsigned)f32_to_bf16(c1) << 16);
        pB.y = (unsigned)f32_to_bf16(c2)  | ((unsigned)f32_to_bf16(c3) << 16);
        *(uint2*)(&x2L[r0 * 200 + c0]) = pA;
        *(uint2*)(&x2L[r1 * 200 + c0]) = pB;
    }
    __syncthreads();

    const int lane = tid & 63;
    const int wave = tid >> 6;
    const int m = lane & 15;
    const int q = lane >> 4;

    bf16x8 bfrag[12];
#pragma unroll
    for (int s = 0; s < 6; ++s)
#pragma unroll
        for (int t = 0; t < 2; ++t)
            bfrag[s * 2 + t] = *(const bf16x8*)(w3t + (16 * t + m) * 192 + 32 * s + q * 8);

    f32x4 acc0 = {0.f, 0.f, 0.f, 0.f}, acc1 = {0.f, 0.f, 0.f, 0.f};
    const int rw = wave * 16;
#pragma unroll
    for (int s = 0; s < 6; ++s) {
        bf16x8 a = *reinterpret_cast<const bf16x8*>(&x2L[(rw + m) * 200 + 32 * s + q * 8]);
        acc0 = __builtin_amdgcn_mfma_f32_16x16x32_bf16(a, bfrag[s * 2 + 0], acc0, 0, 0, 0);
        acc1 = __builtin_amdgcn_mfma_f32_16x16x32_bf16(a, bfrag[s * 2 + 1], acc1, 0, 0, 0);
    }

#pragma unroll
    for (int t = 0; t < 2; ++t) {
        f32x4 acc = (t == 0) ? acc0 : acc1;
        int c = 16 * t + m;
        float s3 = bnc[768 + c], bb3 = bnc[800 + c];
#pragma unroll
        for (int i = 0; i < 4; ++i) {
            int r = rowbase + rw + q * 4 + i;
            if (r < N) {
                int o = r * 32 + c;
                out[o] = fmaf(acc[i], s3, bb3) + feats[o];
            }
        }
    }
}

extern "C" void kernel_launch(void* const* d_in, const int* in_sizes, int n_in,
                              void* d_out, int out_size, void* d_ws, size_t ws_size,
                              hipStream_t stream) {
    const float* feats = (const float*)d_in[0];
    const int*   nbr   = (const int*)d_in[1];
    const float* W1    = (const float*)d_in[2];
    const float* W2    = (const float*)d_in[3];
    const float* W3    = (const float*)d_in[4];
    const float* g1 = (const float*)d_in[5];
    const float* b1 = (const float*)d_in[6];
    const float* m1 = (const float*)d_in[7];
    const float* v1 = (const float*)d_in[8];
    const float* g2 = (const float*)d_in[9];
    const float* b2 = (const float*)d_in[10];
    const float* m2 = (const float*)d_in[11];
    const float* v2 = (const float*)d_in[12];
    const float* g3 = (const float*)d_in[13];
    const float* b3 = (const float*)d_in[14];
    const float* m3 = (const float*)d_in[15];
    const float* v3 = (const float*)d_in[16];
    float* out = (float*)d_out;

    const int N = in_sizes[0] / 32;

    // ws layout: x1 [N*192 u8 = 38.4 MB] | w1t [12,288 B] | w3t [12,288 B] | bnc [3,328 B]
    char* ws = (char*)d_ws;
    unsigned char*  x1  = (unsigned char*)ws;
    unsigned short* w1t = (unsigned short*)(ws + (size_t)N * 192);
    unsigned short* w3t = w1t + 6144;
    float*          bnc = (float*)(w3t + 6144);

    k0_prep<<<dim3(32), dim3(256), 0, stream>>>(
        W1, W3, g1, b1, m1, v1, g2, b2, m2, v2, g3, b3, m3, v3, w1t, w3t, bnc);
    k1_expand<<<dim3((N + 63) / 64), dim3(256), 0, stream>>>(
        feats, w1t, bnc, x1, N);
    k2_fused<<<dim3((N + 47) / 48), dim3(192), 0, stream>>>(
        x1, nbr, W2, w3t, bnc, feats, out, N);
}

// Round 12
// 198.367 us; speedup vs baseline: 1.6910x; 1.0403x over previous
//
#include <hip/hip_runtime.h>

#define EPS 1e-5f

typedef __bf16 bf16x8 __attribute__((ext_vector_type(8)));
typedef float f32x4 __attribute__((ext_vector_type(4)));

union BF8 { bf16x8 v; unsigned short u[8]; uint4 q; };

__device__ inline unsigned short f32_to_bf16(float f) {
    unsigned u = __builtin_bit_cast(unsigned, f);
    return (unsigned short)((u + 0x7FFFu + ((u >> 16) & 1u)) >> 16);
}
__device__ inline float relu6f(float x) { return fminf(fmaxf(x, 0.f), 6.f); }

// ---------------- K1: x1 = uint8-quant(relu6(bn1(feats @ W1))), MFMA ----------------
// R5-proven structure: 128 rows/block, 256 threads, A-frags straight from global,
// B-frags per-lane from L2-hot W1 (no prep kernel), LDS repack -> contiguous uint4
// stores. Block 0 additionally writes w3t + bnc for k2 (k1 finishes before k2 runs).
__global__ __launch_bounds__(256) void k1_expand(
    const float* __restrict__ feats, const float* __restrict__ W1,
    const float* __restrict__ W3,
    const float* __restrict__ g1, const float* __restrict__ b1,
    const float* __restrict__ m1, const float* __restrict__ v1,
    const float* __restrict__ g2, const float* __restrict__ b2,
    const float* __restrict__ m2, const float* __restrict__ v2,
    const float* __restrict__ g3, const float* __restrict__ b3,
    const float* __restrict__ m3, const float* __restrict__ v3,
    unsigned char* __restrict__ x1, unsigned short* __restrict__ w3t,
    float* __restrict__ bnc, int N)
{
    __shared__ __align__(16) unsigned char outB[128 * 224];  // u8, stride 224
    const int tid = threadIdx.x;
    const int rowbase = blockIdx.x * 128;
    const int lane = tid & 63, wave = tid >> 6;
    const int m = lane & 15, q = lane >> 4;

    // ---- block 0: one-time prep for k2 (w3t = W3^T bf16; bnc k2-constants) ----
    if (blockIdx.x == 0) {
#pragma unroll
        for (int j = 0; j < 24; ++j) {
            int i = j * 256 + tid;               // 6144 = w3t[n*192+k] = W3[k*32+n]
            int n = i / 192, k = i - n * 192;
            w3t[i] = f32_to_bf16(W3[k * 32 + n]);
        }
        if (tid < 192) {
            float u = g2[tid] * rsqrtf(v2[tid] + EPS);
            bnc[384 + tid] = u; bnc[576 + tid] = b2[tid] - m2[tid] * u;
            if (tid < 32) {
                float w = g3[tid] * rsqrtf(v3[tid] + EPS);
                bnc[768 + tid] = w; bnc[800 + tid] = b3[tid] - m3[tid] * w;
            }
        }
    }

    // ---- per-lane W1 B-frags + quant-folded bn1 constants (L2-hot, once per block) ----
    const float Q = 255.f / 6.f;
    bf16x8 bf[12];
    float s1c[12], b1c[12];
#pragma unroll
    for (int t = 0; t < 12; ++t) {
        int c = 16 * t + m;
        BF8 tmp;
#pragma unroll
        for (int j = 0; j < 8; ++j)
            tmp.u[j] = f32_to_bf16(W1[(q * 8 + j) * 192 + c]);
        bf[t] = tmp.v;
        float s = g1[c] * rsqrtf(v1[c] + EPS);
        s1c[t] = s * Q;
        b1c[t] = (b1[c] - m1[c] * s) * Q;
    }

    // ---- two row-tiles per wave ----
#pragma unroll
    for (int p = 0; p < 2; ++p) {
        const int tile = wave * 2 + p;            // 0..7
        const int row = rowbase + tile * 16 + m;
        float4 f0 = {0.f,0.f,0.f,0.f}, f1v = {0.f,0.f,0.f,0.f};
        if (row < N) {
            f0  = *(const float4*)(feats + (size_t)row * 32 + q * 8);
            f1v = *(const float4*)(feats + (size_t)row * 32 + q * 8 + 4);
        }
        BF8 af;
        af.u[0] = f32_to_bf16(f0.x);  af.u[1] = f32_to_bf16(f0.y);
        af.u[2] = f32_to_bf16(f0.z);  af.u[3] = f32_to_bf16(f0.w);
        af.u[4] = f32_to_bf16(f1v.x); af.u[5] = f32_to_bf16(f1v.y);
        af.u[6] = f32_to_bf16(f1v.z); af.u[7] = f32_to_bf16(f1v.w);

        f32x4 acc[12];
#pragma unroll
        for (int t = 0; t < 12; ++t) {
            f32x4 z = {0.f, 0.f, 0.f, 0.f};
            acc[t] = __builtin_amdgcn_mfma_f32_16x16x32_bf16(af.v, bf[t], z, 0, 0, 0);
        }

        // epilogue: y*Q clamp [0,255] -> u8 into outB
#pragma unroll
        for (int t = 0; t < 12; ++t) {
            int c = 16 * t + m;
#pragma unroll
            for (int i = 0; i < 4; ++i) {
                int r = tile * 16 + q * 4 + i;
                float y = fmaf(acc[t][i], s1c[t], b1c[t]);
                y = fminf(fmaxf(y, 0.f), 255.f);
                outB[r * 224 + c] = (unsigned char)(y + 0.5f);
            }
        }
    }
    __syncthreads();

    // readout: 128 rows x 12 uint4-chunks = 1536, contiguous global stores
#pragma unroll
    for (int j = 0; j < 6; ++j) {
        int i = j * 256 + tid;
        int r = i / 12, c = i % 12;
        int gr = rowbase + r;
        if (gr < N)
            *(uint4*)(x1 + (size_t)gr * 192 + c * 16) = *(const uint4*)(&outB[r * 224 + c * 16]);
    }
}

// ------- K2: fused depthwise gather (u8) + bn2 + relu6 + project GEMM + bn3 + residual -------
// (verbatim proven 78-79 us version — untouched)
__global__ __launch_bounds__(192) void k2_fused(
    const unsigned char* __restrict__ x1, const int* __restrict__ nbr,
    const float* __restrict__ W2, const unsigned short* __restrict__ w3t,
    const float* __restrict__ bnc, const float* __restrict__ feats,
    float* __restrict__ out, int N)
{
    __shared__ __align__(16) unsigned short x2L[48 * 200];
    __shared__ __align__(16) int offL[48 * 12];
    const int tid = threadIdx.x;
    const int rowbase = blockIdx.x * 48;

    for (int i = tid; i < 432; i += 192) {
        int r = i / 9, k = i - r * 9;
        int n = rowbase + r;
        int idx = (n < N) ? nbr[(size_t)n * 9 + k] : -1;
        offL[r * 12 + k] = (idx < 0) ? -1 : idx * 192;
    }

    const int cg = tid % 48;
    const int slot = tid / 48;
    const int c0 = cg * 4;
    const char* x1b = (const char*)x1 + c0;

    const float DQ = 6.f / 255.f;
    float w2v[9][4];
#pragma unroll
    for (int k = 0; k < 9; ++k) {
        float4 w = *(const float4*)(W2 + k * 192 + c0);
        w2v[k][0] = w.x * DQ; w2v[k][1] = w.y * DQ; w2v[k][2] = w.z * DQ; w2v[k][3] = w.w * DQ;
    }
    float4 s2 = *(const float4*)(bnc + 384 + c0);
    float4 bb2 = *(const float4*)(bnc + 576 + c0);
    __syncthreads();

#pragma unroll
    for (int it = 0; it < 6; ++it) {
        int r0 = it * 8 + slot, r1 = r0 + 4;
        const int* nA = &offL[r0 * 12];
        const int* nB = &offL[r1 * 12];
        int4 a03 = *(const int4*)nA; int4 a47 = *(const int4*)(nA + 4); int a8 = nA[8];
        int4 b03 = *(const int4*)nB; int4 b47 = *(const int4*)(nB + 4); int b8 = nB[8];
        int offA[9] = {a03.x, a03.y, a03.z, a03.w, a47.x, a47.y, a47.z, a47.w, a8};
        int offB[9] = {b03.x, b03.y, b03.z, b03.w, b47.x, b47.y, b47.z, b47.w, b8};
        unsigned gA[9], gB[9];
#pragma unroll
        for (int k = 0; k < 9; ++k) {
            gA[k] = *(const unsigned*)(x1b + (offA[k] < 0 ? 0 : offA[k]));
            gB[k] = *(const unsigned*)(x1b + (offB[k] < 0 ? 0 : offB[k]));
        }
        float a0 = 0.f, a1 = 0.f, a2 = 0.f, a3 = 0.f;
        float c0f = 0.f, c1 = 0.f, c2 = 0.f, c3 = 0.f;
#pragma unroll
        for (int k = 0; k < 9; ++k) {
            unsigned ga = offA[k] >= 0 ? gA[k] : 0u;
            unsigned gb = offB[k] >= 0 ? gB[k] : 0u;
            a0 = fmaf((float)(ga & 0xFF),         w2v[k][0], a0);
            a1 = fmaf((float)((ga >> 8) & 0xFF),  w2v[k][1], a1);
            a2 = fmaf((float)((ga >> 16) & 0xFF), w2v[k][2], a2);
            a3 = fmaf((float)(ga >> 24),          w2v[k][3], a3);
            c0f = fmaf((float)(gb & 0xFF),         w2v[k][0], c0f);
            c1  = fmaf((float)((gb >> 8) & 0xFF),  w2v[k][1], c1);
            c2  = fmaf((float)((gb >> 16) & 0xFF), w2v[k][2], c2);
            c3  = fmaf((float)(gb >> 24),          w2v[k][3], c3);
        }
        a0 = relu6f(fmaf(a0, s2.x, bb2.x));
        a1 = relu6f(fmaf(a1, s2.y, bb2.y));
        a2 = relu6f(fmaf(a2, s2.z, bb2.z));
        a3 = relu6f(fmaf(a3, s2.w, bb2.w));
        c0f = relu6f(fmaf(c0f, s2.x, bb2.x));
        c1  = relu6f(fmaf(c1,  s2.y, bb2.y));
        c2  = relu6f(fmaf(c2,  s2.z, bb2.z));
        c3  = relu6f(fmaf(c3,  s2.w, bb2.w));
        uint2 pA, pB;
        pA.x = (unsigned)f32_to_bf16(a0) | ((unsigned)f32_to_bf16(a1) << 16);
        pA.y = (unsigned)f32_to_bf16(a2) | ((unsigned)f32_to_bf16(a3) << 16);
        pB.x = (unsigned)f32_to_bf16(c0f) | ((unsigned)f32_to_bf16(c1) << 16);
        pB.y = (unsigned)f32_to_bf16(c2)  | ((unsigned)f32_to_bf16(c3) << 16);
        *(uint2*)(&x2L[r0 * 200 + c0]) = pA;
        *(uint2*)(&x2L[r1 * 200 + c0]) = pB;
    }
    __syncthreads();

    const int lane = tid & 63;
    const int wave = tid >> 6;
    const int m = lane & 15;
    const int q = lane >> 4;

    bf16x8 bfrag[12];
#pragma unroll
    for (int s = 0; s < 6; ++s)
#pragma unroll
        for (int t = 0; t < 2; ++t)
            bfrag[s * 2 + t] = *(const bf16x8*)(w3t + (16 * t + m) * 192 + 32 * s + q * 8);

    f32x4 acc0 = {0.f, 0.f, 0.f, 0.f}, acc1 = {0.f, 0.f, 0.f, 0.f};
    const int rw = wave * 16;
#pragma unroll
    for (int s = 0; s < 6; ++s) {
        bf16x8 a = *reinterpret_cast<const bf16x8*>(&x2L[(rw + m) * 200 + 32 * s + q * 8]);
        acc0 = __builtin_amdgcn_mfma_f32_16x16x32_bf16(a, bfrag[s * 2 + 0], acc0, 0, 0, 0);
        acc1 = __builtin_amdgcn_mfma_f32_16x16x32_bf16(a, bfrag[s * 2 + 1], acc1, 0, 0, 0);
    }

#pragma unroll
    for (int t = 0; t < 2; ++t) {
        f32x4 acc = (t == 0) ? acc0 : acc1;
        int c = 16 * t + m;
        float s3 = bnc[768 + c], bb3 = bnc[800 + c];
#pragma unroll
        for (int i = 0; i < 4; ++i) {
            int r = rowbase + rw + q * 4 + i;
            if (r < N) {
                int o = r * 32 + c;
                out[o] = fmaf(acc[i], s3, bb3) + feats[o];
            }
        }
    }
}

extern "C" void kernel_launch(void* const* d_in, const int* in_sizes, int n_in,
                              void* d_out, int out_size, void* d_ws, size_t ws_size,
                              hipStream_t stream) {
    const float* feats = (const float*)d_in[0];
    const int*   nbr   = (const int*)d_in[1];
    const float* W1    = (const float*)d_in[2];
    const float* W2    = (const float*)d_in[3];
    const float* W3    = (const float*)d_in[4];
    const float* g1 = (const float*)d_in[5];
    const float* b1 = (const float*)d_in[6];
    const float* m1 = (const float*)d_in[7];
    const float* v1 = (const float*)d_in[8];
    const float* g2 = (const float*)d_in[9];
    const float* b2 = (const float*)d_in[10];
    const float* m2 = (const float*)d_in[11];
    const float* v2 = (const float*)d_in[12];
    const float* g3 = (const float*)d_in[13];
    const float* b3 = (const float*)d_in[14];
    const float* m3 = (const float*)d_in[15];
    const float* v3 = (const float*)d_in[16];
    float* out = (float*)d_out;

    const int N = in_sizes[0] / 32;

    // ws layout: x1 [N*192 u8 = 38.4 MB] | w3t [12,288 B] | bnc [3,328 B]
    char* ws = (char*)d_ws;
    unsigned char*  x1  = (unsigned char*)ws;
    unsigned short* w3t = (unsigned short*)(ws + (size_t)N * 192);
    float*          bnc = (float*)(w3t + 6144);

    k1_expand<<<dim3((N + 127) / 128), dim3(256), 0, stream>>>(
        feats, W1, W3, g1, b1, m1, v1, g2, b2, m2, v2, g3, b3, m3, v3,
        x1, w3t, bnc, N);
    k2_fused<<<dim3((N + 47) / 48), dim3(192), 0, stream>>>(
        x1, nbr, W2, w3t, bnc, feats, out, N);
}